// Round 8
// baseline (420.388 us; speedup 1.0000x reference)
//
#include <hip/hip_runtime.h>
#include <hip/hip_bf16.h>

#define N_NODES 100000
#define N_EDGES 1600000
#define BSHIFT 8                 // 256 nodes per bucket
#define NB 391                   // ceil(100000/256)
#define BCAP 8192                // bucket capacity (mean 4092 -> huge headroom)

typedef __attribute__((ext_vector_type(8))) short short8;
typedef __attribute__((ext_vector_type(4))) float f32x4;
typedef unsigned short ushort;
typedef unsigned int uint;

__device__ __forceinline__ ushort f2bf(float f) {
    uint u = __float_as_uint(f);
    uint r = (u + 0x7fffu + ((u >> 16) & 1u)) >> 16;
    return (ushort)r;
}
__device__ __forceinline__ float bflo(uint v) { return __uint_as_float(v << 16); }
__device__ __forceinline__ float bfhi(uint v) { return __uint_as_float(v & 0xffff0000u); }

// ---------------- Pass A: partition edges into 391 dst-buckets ----------------

__global__ __launch_bounds__(256) void partA_kernel(const int* __restrict__ src,
                                                    const int* __restrict__ dst,
                                                    uint* __restrict__ packed,
                                                    int* __restrict__ bucket_cnt, int E) {
    constexpr int PER = 16;  // 4096 edges/block
    __shared__ int cnt[NB];
    __shared__ int cur[NB];
    int tid = threadIdx.x;
    for (int i = tid; i < NB; i += 256) cnt[i] = 0;
    __syncthreads();
    int base = blockIdx.x * (256 * PER);
    int d[PER], s[PER];
#pragma unroll
    for (int i = 0; i < PER; i++) {
        int e = base + tid + i * 256;
        if (e < E) {
            d[i] = dst[e];
            s[i] = src[e];
            atomicAdd(&cnt[d[i] >> BSHIFT], 1);
        } else {
            d[i] = -1;
        }
    }
    __syncthreads();
    for (int i = tid; i < NB; i += 256) cur[i] = atomicAdd(&bucket_cnt[i], cnt[i]);
    __syncthreads();
#pragma unroll
    for (int i = 0; i < PER; i++) {
        if (d[i] >= 0) {
            int b = d[i] >> BSHIFT;
            int p = atomicAdd(&cur[b], 1);
            packed[(size_t)b * BCAP + p] = ((uint)(d[i] & 255) << 17) | (uint)s[i];
        }
    }
}

// ---------------- Pass B: per-bucket prefix + degrees + CSR + col fill (single packed read) ----------------

#define KE 20  // 20*256 = 5120 register-held edges/block; bucket mean 4092, 16-sigma safe

__global__ __launch_bounds__(256) void partB_kernel(const uint* __restrict__ packed,
                                                    const int* __restrict__ bucket_cnt,
                                                    int* __restrict__ row_ptr,
                                                    float* __restrict__ inv_deg,
                                                    int* __restrict__ col, int N, int E) {
    __shared__ int deg[256];
    __shared__ int cur[256];
    __shared__ int psum[256];
    __shared__ int sofs;
    int b = blockIdx.x, tid = threadIdx.x;
    int cnt = bucket_cnt[b];
    // bucket offset: parallel sum of bucket_cnt[0..b)
    {
        int part = 0;
        for (int i = tid; i < b; i += 256) part += bucket_cnt[i];
        psum[tid] = part;
        __syncthreads();
        for (int off = 128; off > 0; off >>= 1) {
            if (tid < off) psum[tid] += psum[tid + off];
            __syncthreads();
        }
        if (tid == 0) sofs = psum[0];
        __syncthreads();
    }
    int bofs = sofs;
    const uint* pk = packed + (size_t)b * BCAP;
    deg[tid] = 0;
    __syncthreads();
    uint w[KE];
#pragma unroll
    for (int j = 0; j < KE; j++) {
        int ee = tid + j * 256;
        if (ee < cnt) {
            w[j] = pk[ee];
            atomicAdd(&deg[w[j] >> 17], 1);
        }
    }
    for (int ee = tid + KE * 256; ee < cnt; ee += 256)  // never taken in practice
        atomicAdd(&deg[pk[ee] >> 17], 1);
    __syncthreads();
    int d0 = deg[tid];
    psum[tid] = d0;
    __syncthreads();
    for (int off = 1; off < 256; off <<= 1) {
        int x = psum[tid];
        int y = (tid >= off) ? psum[tid - off] : 0;
        __syncthreads();
        psum[tid] = x + y;
        __syncthreads();
    }
    int excl = psum[tid] - d0;
    cur[tid] = excl;
    int g = (b << BSHIFT) + tid;
    if (g < N) {
        row_ptr[g] = bofs + excl;
        inv_deg[g] = 1.0f / (float)(d0 > 1 ? d0 : 1);
    }
    if (b == 0 && tid == 0) row_ptr[N] = E;
    __syncthreads();
#pragma unroll
    for (int j = 0; j < KE; j++) {
        int ee = tid + j * 256;
        if (ee < cnt) {
            int p = atomicAdd(&cur[w[j] >> 17], 1);
            col[bofs + p] = (int)(w[j] & 0x1FFFFu);
        }
    }
    for (int ee = tid + KE * 256; ee < cnt; ee += 256) {  // never taken in practice
        uint ww = pk[ee];
        int p = atomicAdd(&cur[ww >> 17], 1);
        col[bofs + p] = (int)(ww & 0x1FFFFu);
    }
}

// ---------------- prep: cast x -> bf16  AND  transpose+cast all 3 weight pairs ----------------

#define CAST_BLK 6250  // 100000*128/8 = 1,600,000 8-float units / 256 per block

__global__ __launch_bounds__(256) void prep_kernel(const float* __restrict__ x,
                                                   ushort* __restrict__ xb,
                                                   const float* __restrict__ Ws0,
                                                   const float* __restrict__ Wn0,
                                                   const float* __restrict__ Ws1,
                                                   const float* __restrict__ Wn1,
                                                   const float* __restrict__ Ws2,
                                                   const float* __restrict__ Wn2,
                                                   ushort* __restrict__ BT0,
                                                   ushort* __restrict__ BT1,
                                                   ushort* __restrict__ BT2) {
    int blk = blockIdx.x;
    if (blk < CAST_BLK) {
        long n8 = (long)N_NODES * 128 / 8;
        long g = (long)blk * 256 + threadIdx.x;
        if (g >= n8) return;
        const float4* x4 = (const float4*)x;
        float4 a = x4[g * 2], b = x4[g * 2 + 1];
        uint4 o;
        o.x = (uint)f2bf(a.x) | ((uint)f2bf(a.y) << 16);
        o.y = (uint)f2bf(a.z) | ((uint)f2bf(a.w) << 16);
        o.z = (uint)f2bf(b.x) | ((uint)f2bf(b.y) << 16);
        o.w = (uint)f2bf(b.z) | ((uint)f2bf(b.w) << 16);
        ((uint4*)xb)[g] = o;
        return;
    }
    int idx = (blk - CAST_BLK) * 256 + threadIdx.x;
    const float* Ws;
    const float* Wn;
    ushort* BT;
    int FOUT;
    if (idx < 128 * 256) {
        Ws = Ws0; Wn = Wn0; BT = BT0; FOUT = 128;
    } else if (idx < 2 * 128 * 256) {
        idx -= 128 * 256;
        Ws = Ws1; Wn = Wn1; BT = BT1; FOUT = 128;
    } else if (idx < 2 * 128 * 256 + 64 * 256) {
        idx -= 2 * 128 * 256;
        Ws = Ws2; Wn = Wn2; BT = BT2; FOUT = 64;
    } else {
        return;
    }
    int n = idx >> 8, k = idx & 255;
    float v = (k < 128) ? Ws[k * FOUT + n] : Wn[(k - 128) * FOUT + n];
    BT[idx] = f2bf(v);
}

// ---------------- Fused layer: gather+mean into LDS, then MFMA GEMM ----------------
// Block = 64 dst nodes (4 waves x 16). Phase 1: each wave gathers its 16 nodes'
// neighbor rows (dwordx4, 4 edges in flight) and writes the bf16 mean into LDS
// AGG (row stride 136 ushort = 272 B -> bank shift 4/row, 2-way aliasing = free).
// Phase 2: K-loop kc0..3 A-frag from global h (self term), kc4..7 from LDS AGG.

#define ASTR 136

template <int FOUT, bool RELU, bool OUTBF16>
__global__ __launch_bounds__(256) void fused_layer(const ushort* __restrict__ hb,
                                                   const int* __restrict__ row_ptr,
                                                   const int* __restrict__ col,
                                                   const float* __restrict__ inv_deg,
                                                   const ushort* __restrict__ BTb,
                                                   const float* __restrict__ bias,
                                                   void* __restrict__ outp, int nNodes) {
    constexpr int NT = FOUT / 16;
    constexpr int BSTR = 40;
    __shared__ ushort BT[FOUT * BSTR];
    __shared__ ushort AGG[64 * ASTR];
    int tid = threadIdx.x;
    int wave = tid >> 6, lane = tid & 63;
    int quad = lane >> 4, sub = lane & 15;
    int suboff = sub * 16;
    const char* hbase = (const char*)hb;
    int r0 = blockIdx.x * 64 + wave * 16;

    // ---- Phase 1: gather+mean 16 nodes per wave ----
    for (int i = 0; i < 16; i++) {
        int node = r0 + i;
        if (node >= nNodes) node = nNodes - 1;
        int beg = row_ptr[node], end = row_ptr[node + 1];
        float acc[8];
#pragma unroll
        for (int j = 0; j < 8; j++) acc[j] = 0.f;
        for (int e0 = beg; e0 < end; e0 += 16) {
            int rem = end - e0;
            int idxv[4];
            float msk[4];
#pragma unroll
            for (int j = 0; j < 4; j++) {
                int ii = quad + 4 * j;
                msk[j] = (ii < rem) ? 1.f : 0.f;
                idxv[j] = col[e0 + ((ii < rem) ? ii : 0)];
            }
            uint4 v[4];
#pragma unroll
            for (int j = 0; j < 4; j++)
                v[j] = *(const uint4*)(hbase + (((uint)idxv[j] << 8) + suboff));
#pragma unroll
            for (int j = 0; j < 4; j++) {
                acc[0] += bflo(v[j].x) * msk[j]; acc[1] += bfhi(v[j].x) * msk[j];
                acc[2] += bflo(v[j].y) * msk[j]; acc[3] += bfhi(v[j].y) * msk[j];
                acc[4] += bflo(v[j].z) * msk[j]; acc[5] += bfhi(v[j].z) * msk[j];
                acc[6] += bflo(v[j].w) * msk[j]; acc[7] += bfhi(v[j].w) * msk[j];
            }
        }
#pragma unroll
        for (int j = 0; j < 8; j++) {
            acc[j] += __shfl_xor(acc[j], 16);
            acc[j] += __shfl_xor(acc[j], 32);
        }
        if (quad == 0) {
            float inv = inv_deg[node];
            uint4 o;
            o.x = (uint)f2bf(acc[0] * inv) | ((uint)f2bf(acc[1] * inv) << 16);
            o.y = (uint)f2bf(acc[2] * inv) | ((uint)f2bf(acc[3] * inv) << 16);
            o.z = (uint)f2bf(acc[4] * inv) | ((uint)f2bf(acc[5] * inv) << 16);
            o.w = (uint)f2bf(acc[6] * inv) | ((uint)f2bf(acc[7] * inv) << 16);
            *(uint4*)&AGG[(wave * 16 + i) * ASTR + sub * 8] = o;
        }
    }
    __syncthreads();

    // ---- Phase 2: MFMA GEMM ----
    int m = lane & 15;
    int arow = r0 + m;
    if (arow >= nNodes) arow = nNodes - 1;
    const ushort* hrow = hb + (size_t)arow * 128;

    f32x4 acc[NT];
#pragma unroll
    for (int t = 0; t < NT; t++) acc[t] = (f32x4){0.f, 0.f, 0.f, 0.f};

#pragma unroll
    for (int kc = 0; kc < 8; kc++) {
        __syncthreads();
        constexpr int UNITS = FOUT * 4;  // 16B units
#pragma unroll
        for (int u0 = 0; u0 < UNITS / 256; u0++) {
            int u = tid + u0 * 256;
            int n = u >> 2, ko = (u & 3) * 8;
            short8 v = *(const short8*)(BTb + n * 256 + kc * 32 + ko);
            *(short8*)(&BT[n * BSTR + ko]) = v;
        }
        __syncthreads();
        short8 afrag;
        if (kc < 4) {
            afrag = *(const short8*)(hrow + kc * 32 + quad * 8);
        } else {
            afrag = *(const short8*)(&AGG[(wave * 16 + m) * ASTR + (kc - 4) * 32 + quad * 8]);
        }
#pragma unroll
        for (int t = 0; t < NT; t++) {
            short8 bfrag = *(const short8*)(&BT[(t * 16 + m) * BSTR + quad * 8]);
            acc[t] = __builtin_amdgcn_mfma_f32_16x16x32_bf16(afrag, bfrag, acc[t], 0, 0, 0);
        }
    }

#pragma unroll
    for (int reg = 0; reg < 4; reg++) {
        int orow = r0 + quad * 4 + reg;
        if (orow < nNodes) {
#pragma unroll
            for (int t = 0; t < NT; t++) {
                int j = t * 16 + m;
                float v = acc[t][reg] + bias[j];
                if (RELU) v = fmaxf(v, 0.f);
                if (OUTBF16)
                    ((ushort*)outp)[(size_t)orow * FOUT + j] = f2bf(v);
                else
                    ((float*)outp)[(size_t)orow * FOUT + j] = v;
            }
        }
    }
}

extern "C" void kernel_launch(void* const* d_in, const int* in_sizes, int n_in,
                              void* d_out, int out_size, void* d_ws, size_t ws_size,
                              hipStream_t stream) {
    const float* x   = (const float*)d_in[0];
    const int* src   = (const int*)d_in[1];
    const int* dst   = (const int*)d_in[2];
    const float* Ws0 = (const float*)d_in[3];
    const float* Wn0 = (const float*)d_in[4];
    const float* b0  = (const float*)d_in[5];
    const float* Ws1 = (const float*)d_in[6];
    const float* Wn1 = (const float*)d_in[7];
    const float* b1  = (const float*)d_in[8];
    const float* Ws2 = (const float*)d_in[9];
    const float* Wn2 = (const float*)d_in[10];
    const float* b2  = (const float*)d_in[11];
    float* out = (float*)d_out;

    const int N = N_NODES, E = N_EDGES;

    char* p = (char*)d_ws;
    auto take = [&](size_t bytes) {
        void* r = (void*)p;
        p += (bytes + 255) & ~(size_t)255;
        return r;
    };
    uint* packed    = (uint*)take((size_t)NB * BCAP * 4);  // 12.8 MB
    int* bucket_cnt = (int*)take((size_t)NB * 4);
    int* row_ptr    = (int*)take((size_t)(N + 1) * 4);
    int* col        = (int*)take((size_t)E * 4);
    float* inv_deg  = (float*)take((size_t)N * 4);
    ushort* xb      = (ushort*)take((size_t)N * 128 * 2);
    ushort* h1b     = (ushort*)take((size_t)N * 128 * 2);
    ushort* BT0     = (ushort*)take((size_t)128 * 256 * 2);
    ushort* BT1     = (ushort*)take((size_t)128 * 256 * 2);
    ushort* BT2     = (ushort*)take((size_t)64 * 256 * 2);

    // --- CSR build via bucketed partition ---
    hipMemsetAsync(bucket_cnt, 0, (size_t)NB * 4, stream);
    int nblkA = (E + 4096 - 1) / 4096;
    partA_kernel<<<nblkA, 256, 0, stream>>>(src, dst, packed, bucket_cnt, E);
    partB_kernel<<<NB, 256, 0, stream>>>(packed, bucket_cnt, row_ptr, inv_deg, col, N, E);

    // --- fused casts / weight transposes ---
    prep_kernel<<<CAST_BLK + 320, 256, 0, stream>>>(x, xb, Ws0, Wn0, Ws1, Wn1, Ws2, Wn2,
                                                    BT0, BT1, BT2);

    int grid = (N + 63) / 64;

    // --- layer 0: xb -> h1b ---
    fused_layer<128, true, true><<<grid, 256, 0, stream>>>(xb, row_ptr, col, inv_deg,
                                                           BT0, b0, h1b, N);
    // --- layer 1: h1b -> xb (reuse input buffer) ---
    fused_layer<128, true, true><<<grid, 256, 0, stream>>>(h1b, row_ptr, col, inv_deg,
                                                           BT1, b1, xb, N);
    // --- layer 2: xb -> out (fp32) ---
    fused_layer<64, false, false><<<grid, 256, 0, stream>>>(xb, row_ptr, col, inv_deg,
                                                            BT2, b2, out, N);
}

// Round 9
// 360.909 us; speedup vs baseline: 1.1648x; 1.1648x over previous
//
#include <hip/hip_runtime.h>
#include <hip/hip_bf16.h>

#define N_NODES 100000
#define N_EDGES 1600000
#define BSHIFT 8                 // 256 nodes per bucket
#define NB 391                   // ceil(100000/256)
#define BCAP 8192                // bucket capacity (mean 4092 -> huge headroom)

typedef __attribute__((ext_vector_type(8))) short short8;
typedef __attribute__((ext_vector_type(4))) float f32x4;
typedef unsigned short ushort;
typedef unsigned int uint;

__device__ __forceinline__ ushort f2bf(float f) {
    uint u = __float_as_uint(f);
    uint r = (u + 0x7fffu + ((u >> 16) & 1u)) >> 16;
    return (ushort)r;
}
__device__ __forceinline__ float bflo(uint v) { return __uint_as_float(v << 16); }
__device__ __forceinline__ float bfhi(uint v) { return __uint_as_float(v & 0xffff0000u); }

// ---------------- fused partA (blocks 0..390) + prep (rest) ----------------
// partA: per-wave replicated LDS histograms + cursors -> no cross-wave LDS atomic
// contention; one global atomic per (block,bucket).
// prep: cast x -> bf16 (6250 blocks), then BT0/BT1 (128 blocks each), BT2' (64).

#define CAST_BLK 6250
#define PREP_BLK (CAST_BLK + 128 + 128 + 64)

__global__ __launch_bounds__(256) void fusedA_kernel(const int* __restrict__ src,
                                                     const int* __restrict__ dst,
                                                     uint* __restrict__ packed,
                                                     int* __restrict__ bucket_cnt, int E,
                                                     const float* __restrict__ x,
                                                     ushort* __restrict__ xb,
                                                     const float* __restrict__ Ws0,
                                                     const float* __restrict__ Wn0,
                                                     const float* __restrict__ Ws1,
                                                     const float* __restrict__ Wn1,
                                                     const float* __restrict__ Ws2,
                                                     const float* __restrict__ Wn2,
                                                     ushort* __restrict__ BT0,
                                                     ushort* __restrict__ BT1,
                                                     ushort* __restrict__ BT2) {
    __shared__ int cnt4[4][NB];
    __shared__ int cur4[4][NB];
    int tid = threadIdx.x;
    if (blockIdx.x < NB) {
        constexpr int PER = 16;  // 4096 edges/block
        int w = tid >> 6;
        for (int i = tid; i < 4 * NB; i += 256) ((int*)cnt4)[i] = 0;
        __syncthreads();
        int base = blockIdx.x * (256 * PER);
        int d[PER], s[PER];
#pragma unroll
        for (int i = 0; i < PER; i++) {
            int e = base + tid + i * 256;
            if (e < E) {
                d[i] = dst[e];
                s[i] = src[e];
                atomicAdd(&cnt4[w][d[i] >> BSHIFT], 1);
            } else {
                d[i] = -1;
            }
        }
        __syncthreads();
        for (int i = tid; i < NB; i += 256) {
            int c0 = cnt4[0][i], c1 = cnt4[1][i], c2 = cnt4[2][i], c3 = cnt4[3][i];
            int b0 = atomicAdd(&bucket_cnt[i], c0 + c1 + c2 + c3);
            cur4[0][i] = b0;
            cur4[1][i] = b0 + c0;
            cur4[2][i] = b0 + c0 + c1;
            cur4[3][i] = b0 + c0 + c1 + c2;
        }
        __syncthreads();
#pragma unroll
        for (int i = 0; i < PER; i++) {
            if (d[i] >= 0) {
                int b = d[i] >> BSHIFT;
                int p = atomicAdd(&cur4[w][b], 1);
                packed[(size_t)b * BCAP + p] = ((uint)(d[i] & 255) << 17) | (uint)s[i];
            }
        }
        return;
    }
    int blk = blockIdx.x - NB;
    if (blk < CAST_BLK) {
        long n8 = (long)N_NODES * 128 / 8;
        long g = (long)blk * 256 + tid;
        if (g >= n8) return;
        const float4* x4 = (const float4*)x;
        float4 a = x4[g * 2], b = x4[g * 2 + 1];
        uint4 o;
        o.x = (uint)f2bf(a.x) | ((uint)f2bf(a.y) << 16);
        o.y = (uint)f2bf(a.z) | ((uint)f2bf(a.w) << 16);
        o.z = (uint)f2bf(b.x) | ((uint)f2bf(b.y) << 16);
        o.w = (uint)f2bf(b.z) | ((uint)f2bf(b.w) << 16);
        ((uint4*)xb)[g] = o;
        return;
    }
    int idx = (blk - CAST_BLK) * 256 + tid;
    if (idx < 128 * 256) {
        // BT0[n*256+k]
        int n = idx >> 8, k = idx & 255;
        float v = (k < 128) ? Ws0[k * 128 + n] : Wn0[(k - 128) * 128 + n];
        BT0[idx] = f2bf(v);
    } else if (idx < 2 * 128 * 256) {
        idx -= 128 * 256;
        int n = idx >> 8, k = idx & 255;
        float v = (k < 128) ? Ws1[k * 128 + n] : Wn1[(k - 128) * 128 + n];
        BT1[idx] = f2bf(v);
    } else if (idx < 2 * 128 * 256 + 128 * 128) {
        idx -= 2 * 128 * 256;
        // BT2'[n*128+k]: n<64 -> Ws2 col n (zs), n>=64 -> Wn2 col n-64 (y2)
        int n = idx >> 7, k = idx & 127;
        float v = (n < 64) ? Ws2[k * 64 + n] : Wn2[k * 64 + (n - 64)];
        BT2[idx] = f2bf(v);
    }
}

// ---------------- Pass B: per-bucket prefix + degrees + CSR + col fill ----------------

#define KE 20  // 20*256 = 5120 register-held edges/block; bucket mean 4092, 16-sigma safe

__global__ __launch_bounds__(256) void partB_kernel(const uint* __restrict__ packed,
                                                    const int* __restrict__ bucket_cnt,
                                                    int* __restrict__ row_ptr,
                                                    float* __restrict__ inv_deg,
                                                    int* __restrict__ col, int N, int E) {
    __shared__ int deg[256];
    __shared__ int cur[256];
    __shared__ int psum[256];
    __shared__ int sofs;
    int b = blockIdx.x, tid = threadIdx.x;
    int cnt = bucket_cnt[b];
    {
        int part = 0;
        for (int i = tid; i < b; i += 256) part += bucket_cnt[i];
        psum[tid] = part;
        __syncthreads();
        for (int off = 128; off > 0; off >>= 1) {
            if (tid < off) psum[tid] += psum[tid + off];
            __syncthreads();
        }
        if (tid == 0) sofs = psum[0];
        __syncthreads();
    }
    int bofs = sofs;
    const uint* pk = packed + (size_t)b * BCAP;
    deg[tid] = 0;
    __syncthreads();
    uint w[KE];
#pragma unroll
    for (int j = 0; j < KE; j++) {
        int ee = tid + j * 256;
        if (ee < cnt) {
            w[j] = pk[ee];
            atomicAdd(&deg[w[j] >> 17], 1);
        }
    }
    for (int ee = tid + KE * 256; ee < cnt; ee += 256)
        atomicAdd(&deg[pk[ee] >> 17], 1);
    __syncthreads();
    int d0 = deg[tid];
    psum[tid] = d0;
    __syncthreads();
    for (int off = 1; off < 256; off <<= 1) {
        int x = psum[tid];
        int y = (tid >= off) ? psum[tid - off] : 0;
        __syncthreads();
        psum[tid] = x + y;
        __syncthreads();
    }
    int excl = psum[tid] - d0;
    cur[tid] = excl;
    int g = (b << BSHIFT) + tid;
    if (g < N) {
        row_ptr[g] = bofs + excl;
        inv_deg[g] = 1.0f / (float)(d0 > 1 ? d0 : 1);
    }
    if (b == 0 && tid == 0) row_ptr[N] = E;
    __syncthreads();
#pragma unroll
    for (int j = 0; j < KE; j++) {
        int ee = tid + j * 256;
        if (ee < cnt) {
            int p = atomicAdd(&cur[w[j] >> 17], 1);
            col[bofs + p] = (int)(w[j] & 0x1FFFFu);
        }
    }
    for (int ee = tid + KE * 256; ee < cnt; ee += 256) {
        uint ww = pk[ee];
        int p = atomicAdd(&cur[ww >> 17], 1);
        col[bofs + p] = (int)(ww & 0x1FFFFu);
    }
}

// ---------------- Aggregation (128-bf16 rows): one wave/node; 16 edges / 4 dwordx4 in flight ----------------

__global__ __launch_bounds__(256) void agg_kernel(const ushort* __restrict__ hb,
                                                  const int* __restrict__ row_ptr,
                                                  const int* __restrict__ col,
                                                  const float* __restrict__ inv_deg,
                                                  ushort* __restrict__ aggb, int n) {
    int node = (int)((blockIdx.x * blockDim.x + threadIdx.x) >> 6);
    int lane = threadIdx.x & 63;
    if (node >= n) return;
    int quad = lane >> 4;
    int sub = lane & 15;
    const char* hbase = (const char*)hb;
    int beg = row_ptr[node], end = row_ptr[node + 1];
    float acc[8];
#pragma unroll
    for (int j = 0; j < 8; j++) acc[j] = 0.f;
    int suboff = sub * 16;
    for (int e0 = beg; e0 < end; e0 += 16) {
        int rem = end - e0;
        int idxv[4];
        float msk[4];
#pragma unroll
        for (int j = 0; j < 4; j++) {
            int i = quad + 4 * j;
            msk[j] = (i < rem) ? 1.f : 0.f;
            idxv[j] = col[e0 + ((i < rem) ? i : 0)];
        }
        uint4 v[4];
#pragma unroll
        for (int j = 0; j < 4; j++)
            v[j] = *(const uint4*)(hbase + (((uint)idxv[j] << 8) + suboff));
#pragma unroll
        for (int j = 0; j < 4; j++) {
            acc[0] += bflo(v[j].x) * msk[j]; acc[1] += bfhi(v[j].x) * msk[j];
            acc[2] += bflo(v[j].y) * msk[j]; acc[3] += bfhi(v[j].y) * msk[j];
            acc[4] += bflo(v[j].z) * msk[j]; acc[5] += bfhi(v[j].z) * msk[j];
            acc[6] += bflo(v[j].w) * msk[j]; acc[7] += bfhi(v[j].w) * msk[j];
        }
    }
#pragma unroll
    for (int j = 0; j < 8; j++) {
        acc[j] += __shfl_xor(acc[j], 16);
        acc[j] += __shfl_xor(acc[j], 32);
    }
    if (quad == 0) {
        float inv = inv_deg[node];
        uint4 o;
        o.x = (uint)f2bf(acc[0] * inv) | ((uint)f2bf(acc[1] * inv) << 16);
        o.y = (uint)f2bf(acc[2] * inv) | ((uint)f2bf(acc[3] * inv) << 16);
        o.z = (uint)f2bf(acc[4] * inv) | ((uint)f2bf(acc[5] * inv) << 16);
        o.w = (uint)f2bf(acc[6] * inv) | ((uint)f2bf(acc[7] * inv) << 16);
        *(uint4*)((char*)aggb + (size_t)node * 256 + suboff) = o;
    }
}

// ---------------- MFMA GEMM layers 0/1: out = [h|agg] @ BT^T + b; M-tile 128 ----------------
// 4 waves x 32 rows (2 x 16-row frags/wave): B-frag reused for 2 MFMAs, B staged once/chunk.

template <int FOUT, bool RELU>
__global__ __launch_bounds__(256) void mfma_gemm(const ushort* __restrict__ hb,
                                                 const ushort* __restrict__ aggb,
                                                 const ushort* __restrict__ BTb,
                                                 const float* __restrict__ bias,
                                                 ushort* __restrict__ outp, int nNodes) {
    constexpr int NT = FOUT / 16;
    constexpr int BSTR = 40;
    __shared__ ushort BT[FOUT * BSTR];
    int tid = threadIdx.x;
    int wave = tid >> 6, lane = tid & 63;
    int m = lane & 15, quad = lane >> 4;
    int r0 = blockIdx.x * 128 + wave * 32;
    int arow0 = r0 + m;       if (arow0 >= nNodes) arow0 = nNodes - 1;
    int arow1 = r0 + 16 + m;  if (arow1 >= nNodes) arow1 = nNodes - 1;
    const ushort* hrow0 = hb + (size_t)arow0 * 128;
    const ushort* grow0 = aggb + (size_t)arow0 * 128;
    const ushort* hrow1 = hb + (size_t)arow1 * 128;
    const ushort* grow1 = aggb + (size_t)arow1 * 128;

    f32x4 acc[2][NT];
#pragma unroll
    for (int h = 0; h < 2; h++)
#pragma unroll
        for (int t = 0; t < NT; t++) acc[h][t] = (f32x4){0.f, 0.f, 0.f, 0.f};

#pragma unroll
    for (int kc = 0; kc < 8; kc++) {
        __syncthreads();
        constexpr int UNITS = FOUT * 4;  // 16B units
#pragma unroll
        for (int u0 = 0; u0 < UNITS / 256; u0++) {
            int u = tid + u0 * 256;
            int n = u >> 2, ko = (u & 3) * 8;
            short8 v = *(const short8*)(BTb + n * 256 + kc * 32 + ko);
            *(short8*)(&BT[n * BSTR + ko]) = v;
        }
        __syncthreads();
        int kg = kc * 32 + quad * 8;
        const ushort* ap0 = (kg < 128) ? (hrow0 + kg) : (grow0 + (kg - 128));
        const ushort* ap1 = (kg < 128) ? (hrow1 + kg) : (grow1 + (kg - 128));
        short8 af0 = *(const short8*)ap0;
        short8 af1 = *(const short8*)ap1;
#pragma unroll
        for (int t = 0; t < NT; t++) {
            short8 bfrag = *(const short8*)(&BT[(t * 16 + m) * BSTR + quad * 8]);
            acc[0][t] = __builtin_amdgcn_mfma_f32_16x16x32_bf16(af0, bfrag, acc[0][t], 0, 0, 0);
            acc[1][t] = __builtin_amdgcn_mfma_f32_16x16x32_bf16(af1, bfrag, acc[1][t], 0, 0, 0);
        }
    }

#pragma unroll
    for (int h = 0; h < 2; h++)
#pragma unroll
        for (int reg = 0; reg < 4; reg++) {
            int orow = r0 + h * 16 + quad * 4 + reg;
            if (orow < nNodes) {
#pragma unroll
                for (int t = 0; t < NT; t++) {
                    int j = t * 16 + m;
                    float v = acc[h][t][reg] + bias[j];
                    if (RELU) v = fmaxf(v, 0.f);
                    outp[(size_t)orow * FOUT + j] = f2bf(v);
                }
            }
        }
}

// ---------------- Layer-2 GEMM: zs = h@Ws2 + b2 (fp32), y2 = h@Wn2 (bf16); K=128 ----------------

__global__ __launch_bounds__(256) void gemm2a_kernel(const ushort* __restrict__ hb,
                                                     const ushort* __restrict__ BT2b,
                                                     const float* __restrict__ bias,
                                                     float* __restrict__ zs,
                                                     ushort* __restrict__ y2, int nNodes) {
    constexpr int NT = 8;  // 128 output cols: 0..63 zs, 64..127 y2
    constexpr int BSTR = 40;
    __shared__ ushort BT[128 * BSTR];
    int tid = threadIdx.x;
    int wave = tid >> 6, lane = tid & 63;
    int m = lane & 15, quad = lane >> 4;
    int r0 = blockIdx.x * 128 + wave * 32;
    int arow0 = r0 + m;       if (arow0 >= nNodes) arow0 = nNodes - 1;
    int arow1 = r0 + 16 + m;  if (arow1 >= nNodes) arow1 = nNodes - 1;
    const ushort* hrow0 = hb + (size_t)arow0 * 128;
    const ushort* hrow1 = hb + (size_t)arow1 * 128;

    f32x4 acc[2][NT];
#pragma unroll
    for (int h = 0; h < 2; h++)
#pragma unroll
        for (int t = 0; t < NT; t++) acc[h][t] = (f32x4){0.f, 0.f, 0.f, 0.f};

#pragma unroll
    for (int kc = 0; kc < 4; kc++) {
        __syncthreads();
#pragma unroll
        for (int u0 = 0; u0 < 2; u0++) {  // 128 rows * 4 units = 512 / 256
            int u = tid + u0 * 256;
            int n = u >> 2, ko = (u & 3) * 8;
            short8 v = *(const short8*)(BT2b + n * 128 + kc * 32 + ko);
            *(short8*)(&BT[n * BSTR + ko]) = v;
        }
        __syncthreads();
        int kg = kc * 32 + quad * 8;
        short8 af0 = *(const short8*)(hrow0 + kg);
        short8 af1 = *(const short8*)(hrow1 + kg);
#pragma unroll
        for (int t = 0; t < NT; t++) {
            short8 bfrag = *(const short8*)(&BT[(t * 16 + m) * BSTR + quad * 8]);
            acc[0][t] = __builtin_amdgcn_mfma_f32_16x16x32_bf16(af0, bfrag, acc[0][t], 0, 0, 0);
            acc[1][t] = __builtin_amdgcn_mfma_f32_16x16x32_bf16(af1, bfrag, acc[1][t], 0, 0, 0);
        }
    }

#pragma unroll
    for (int h = 0; h < 2; h++)
#pragma unroll
        for (int reg = 0; reg < 4; reg++) {
            int orow = r0 + h * 16 + quad * 4 + reg;
            if (orow < nNodes) {
#pragma unroll
                for (int t = 0; t < 4; t++) {  // zs half
                    int j = t * 16 + m;
                    zs[(size_t)orow * 64 + j] = acc[h][t][reg] + bias[j];
                }
#pragma unroll
                for (int t = 4; t < 8; t++) {  // y2 half
                    int j = (t - 4) * 16 + m;
                    y2[(size_t)orow * 64 + j] = f2bf(acc[h][t][reg]);
                }
            }
        }
}

// ---------------- agg2: gather y2 (128B rows), out = zs + mean(y2); fp32 out ----------------
// lane = (oct, sub): oct=lane>>3 picks edge slot, sub=lane&7 picks 16B chunk. 16 edges/iter.

__global__ __launch_bounds__(256) void agg2_kernel(const ushort* __restrict__ y2,
                                                   const int* __restrict__ row_ptr,
                                                   const int* __restrict__ col,
                                                   const float* __restrict__ inv_deg,
                                                   const float* __restrict__ zs,
                                                   float* __restrict__ out, int n) {
    int node = (int)((blockIdx.x * blockDim.x + threadIdx.x) >> 6);
    int lane = threadIdx.x & 63;
    if (node >= n) return;
    int oct = lane >> 3;
    int sub = lane & 7;
    const char* ybase = (const char*)y2;
    int beg = row_ptr[node], end = row_ptr[node + 1];
    float acc[8];
#pragma unroll
    for (int j = 0; j < 8; j++) acc[j] = 0.f;
    int suboff = sub * 16;
    for (int e0 = beg; e0 < end; e0 += 16) {
        int rem = end - e0;
        int idxv[2];
        float msk[2];
#pragma unroll
        for (int j = 0; j < 2; j++) {
            int i = oct + 8 * j;
            msk[j] = (i < rem) ? 1.f : 0.f;
            idxv[j] = col[e0 + ((i < rem) ? i : 0)];
        }
        uint4 v[2];
#pragma unroll
        for (int j = 0; j < 2; j++)
            v[j] = *(const uint4*)(ybase + (((uint)idxv[j] << 7) + suboff));
#pragma unroll
        for (int j = 0; j < 2; j++) {
            acc[0] += bflo(v[j].x) * msk[j]; acc[1] += bfhi(v[j].x) * msk[j];
            acc[2] += bflo(v[j].y) * msk[j]; acc[3] += bfhi(v[j].y) * msk[j];
            acc[4] += bflo(v[j].z) * msk[j]; acc[5] += bfhi(v[j].z) * msk[j];
            acc[6] += bflo(v[j].w) * msk[j]; acc[7] += bfhi(v[j].w) * msk[j];
        }
    }
#pragma unroll
    for (int j = 0; j < 8; j++) {
        acc[j] += __shfl_xor(acc[j], 8);
        acc[j] += __shfl_xor(acc[j], 16);
        acc[j] += __shfl_xor(acc[j], 32);
    }
    if (oct == 0) {
        float inv = inv_deg[node];
        const float4* z = (const float4*)(zs + (size_t)node * 64 + sub * 8);
        float4 z0 = z[0], z1 = z[1];
        float4 o0, o1;
        o0.x = z0.x + acc[0] * inv; o0.y = z0.y + acc[1] * inv;
        o0.z = z0.z + acc[2] * inv; o0.w = z0.w + acc[3] * inv;
        o1.x = z1.x + acc[4] * inv; o1.y = z1.y + acc[5] * inv;
        o1.z = z1.z + acc[6] * inv; o1.w = z1.w + acc[7] * inv;
        float4* op = (float4*)(out + (size_t)node * 64 + sub * 8);
        op[0] = o0; op[1] = o1;
    }
}

extern "C" void kernel_launch(void* const* d_in, const int* in_sizes, int n_in,
                              void* d_out, int out_size, void* d_ws, size_t ws_size,
                              hipStream_t stream) {
    const float* x   = (const float*)d_in[0];
    const int* src   = (const int*)d_in[1];
    const int* dst   = (const int*)d_in[2];
    const float* Ws0 = (const float*)d_in[3];
    const float* Wn0 = (const float*)d_in[4];
    const float* b0  = (const float*)d_in[5];
    const float* Ws1 = (const float*)d_in[6];
    const float* Wn1 = (const float*)d_in[7];
    const float* b1  = (const float*)d_in[8];
    const float* Ws2 = (const float*)d_in[9];
    const float* Wn2 = (const float*)d_in[10];
    const float* b2  = (const float*)d_in[11];
    float* out = (float*)d_out;

    const int N = N_NODES, E = N_EDGES;

    char* p = (char*)d_ws;
    auto take = [&](size_t bytes) {
        void* r = (void*)p;
        p += (bytes + 255) & ~(size_t)255;
        return r;
    };
    uint* packed    = (uint*)take((size_t)NB * BCAP * 4);  // 12.8 MB; reused as y2 in layer 2
    int* bucket_cnt = (int*)take((size_t)NB * 4);
    int* row_ptr    = (int*)take((size_t)(N + 1) * 4);
    int* col        = (int*)take((size_t)E * 4);
    float* inv_deg  = (float*)take((size_t)N * 4);
    ushort* xb      = (ushort*)take((size_t)N * 128 * 2);
    ushort* h1b     = (ushort*)take((size_t)N * 128 * 2);
    ushort* aggb    = (ushort*)take((size_t)N * 128 * 2);  // reused as zs (fp32, same size)
    ushort* BT0     = (ushort*)take((size_t)128 * 256 * 2);
    ushort* BT1     = (ushort*)take((size_t)128 * 256 * 2);
    ushort* BT2     = (ushort*)take((size_t)128 * 128 * 2);
    ushort* y2 = (ushort*)packed;   // packed dead after partB
    float* zs = (float*)aggb;       // aggb dead after gemm layer 1

    // --- CSR build (partA) + casts/transposes (prep) in one dispatch ---
    hipMemsetAsync(bucket_cnt, 0, (size_t)NB * 4, stream);
    fusedA_kernel<<<NB + PREP_BLK, 256, 0, stream>>>(src, dst, packed, bucket_cnt, E,
                                                     x, xb, Ws0, Wn0, Ws1, Wn1, Ws2, Wn2,
                                                     BT0, BT1, BT2);
    partB_kernel<<<NB, 256, 0, stream>>>(packed, bucket_cnt, row_ptr, inv_deg, col, N, E);

    int aggGrid = (int)(((long)N * 64 + 255) / 256);
    int gemmGrid = (N + 127) / 128;

    // --- layer 0: xb -> h1b ---
    agg_kernel<<<aggGrid, 256, 0, stream>>>(xb, row_ptr, col, inv_deg, aggb, N);
    mfma_gemm<128, true><<<gemmGrid, 256, 0, stream>>>(xb, aggb, BT0, b0, h1b, N);
    // --- layer 1: h1b -> xb ---
    agg_kernel<<<aggGrid, 256, 0, stream>>>(h1b, row_ptr, col, inv_deg, aggb, N);
    mfma_gemm<128, true><<<gemmGrid, 256, 0, stream>>>(h1b, aggb, BT1, b1, xb, N);
    // --- layer 2 (transform-then-aggregate): xb -> zs,y2 -> out ---
    gemm2a_kernel<<<gemmGrid, 256, 0, stream>>>(xb, BT2, b2, zs, y2, N);
    agg2_kernel<<<aggGrid, 256, 0, stream>>>(y2, row_ptr, col, inv_deg, zs, out, N);
}